// Round 1
// baseline (683.443 us; speedup 1.0000x reference)
//
#include <hip/hip_runtime.h>
#include <hip/hip_bf16.h>

// Problem constants (fixed by reference)
#define B_  4
#define E_  100000
#define N_  10000
#define NR_ 6
#define H_  256
#define D_  256
#define OUT_ 128

// ---------------------------------------------------------------------------
// Kernel 1: fused rbf-projection + elementwise mul + scatter-add into agg
// grid = E_ blocks, 256 threads (one thread per h)
// agg[b][node][h] += (sum_r rbf[e][r] * W_rbf[r][h]) * x[b][e][h]
// ---------------------------------------------------------------------------
__global__ __launch_bounds__(256) void scatter_kernel(
    const float* __restrict__ x, const float* __restrict__ rbf,
    const int* __restrict__ idx, const float* __restrict__ W_rbf,
    float* __restrict__ agg) {
  const int e = blockIdx.x;
  const int h = threadIdx.x;
  const int node = idx[e];

  // rbf row is uniform across the block -> scalar loads / L1 broadcast
  float rp = 0.0f;
#pragma unroll
  for (int r = 0; r < NR_; ++r) {
    rp += rbf[e * NR_ + r] * W_rbf[r * H_ + h];
  }

#pragma unroll
  for (int b = 0; b < B_; ++b) {
    const float v = x[((size_t)b * E_ + e) * H_ + h] * rp;
    atomicAdd(&agg[((size_t)b * N_ + node) * H_ + h], v);
  }
}

// ---------------------------------------------------------------------------
// Kernel 2: tiled f32 GEMM  C[M,N] = act(A[M,256] @ W[256,N] + bias)
// 64x64 tile per block, 256 threads, 4x4 per thread. K fixed at 256.
// BIAS_ACT: add bias + SiLU.
// ---------------------------------------------------------------------------
template <bool BIAS_ACT>
__global__ __launch_bounds__(256) void gemm_kernel(
    const float* __restrict__ A, const float* __restrict__ W,
    const float* __restrict__ bias, float* __restrict__ C, int N) {
  const int K = 256;
  // A tile stored K-major with pad: As[k][r], row stride 68 floats
  // (68 % 4 == 0 keeps float4 reads 16B-aligned; pad spreads banks)
  __shared__ float As[32][68];
  __shared__ float Bs[32][64];

  const int row0 = blockIdx.x * 64;
  const int col0 = blockIdx.y * 64;
  const int tid = threadIdx.x;
  const int tr4 = (tid >> 4) << 2;  // row offset within tile (0..60)
  const int tc4 = (tid & 15) << 2;  // col offset within tile (0..60)

  float acc[4][4] = {};

  for (int k0 = 0; k0 < K; k0 += 32) {
    // --- stage A tile: 64 rows x 32 k, as float4 global loads ---
#pragma unroll
    for (int t = 0; t < 2; ++t) {
      const int i = tid + t * 256;   // 0..511
      const int r = i >> 3;          // 0..63
      const int kg = i & 7;          // 0..7 (group of 4 k)
      const float4 v = *reinterpret_cast<const float4*>(
          &A[(size_t)(row0 + r) * K + k0 + kg * 4]);
      As[kg * 4 + 0][r] = v.x;
      As[kg * 4 + 1][r] = v.y;
      As[kg * 4 + 2][r] = v.z;
      As[kg * 4 + 3][r] = v.w;
    }
    // --- stage B tile: 32 k x 64 cols, float4 both sides ---
#pragma unroll
    for (int t = 0; t < 2; ++t) {
      const int i = tid + t * 256;   // 0..511
      const int kk = i >> 4;         // 0..31
      const int cg = i & 15;         // 0..15
      const float4 v = *reinterpret_cast<const float4*>(
          &W[(size_t)(k0 + kk) * N + col0 + cg * 4]);
      *reinterpret_cast<float4*>(&Bs[kk][cg * 4]) = v;
    }
    __syncthreads();

#pragma unroll
    for (int kk = 0; kk < 32; ++kk) {
      const float4 a = *reinterpret_cast<const float4*>(&As[kk][tr4]);
      const float4 b = *reinterpret_cast<const float4*>(&Bs[kk][tc4]);
      const float av[4] = {a.x, a.y, a.z, a.w};
      const float bv[4] = {b.x, b.y, b.z, b.w};
#pragma unroll
      for (int i2 = 0; i2 < 4; ++i2)
#pragma unroll
        for (int j = 0; j < 4; ++j) acc[i2][j] += av[i2] * bv[j];
    }
    __syncthreads();
  }

  // --- epilogue ---
  float bv[4] = {0.f, 0.f, 0.f, 0.f};
  if (BIAS_ACT) {
#pragma unroll
    for (int j = 0; j < 4; ++j) bv[j] = bias[col0 + tc4 + j];
  }
#pragma unroll
  for (int i2 = 0; i2 < 4; ++i2) {
#pragma unroll
    for (int j = 0; j < 4; ++j) {
      float v = acc[i2][j];
      if (BIAS_ACT) {
        v += bv[j];
        v = v / (1.0f + __expf(-v));  // SiLU
      }
      C[(size_t)(row0 + tr4 + i2) * N + col0 + tc4 + j] = v;
    }
  }
}

// ---------------------------------------------------------------------------
extern "C" void kernel_launch(void* const* d_in, const int* in_sizes, int n_in,
                              void* d_out, int out_size, void* d_ws,
                              size_t ws_size, hipStream_t stream) {
  const float* x     = (const float*)d_in[0];  // [B,E,H]
  const float* rbf   = (const float*)d_in[1];  // [E,NR]
  const int*   idx   = (const int*)d_in[2];    // [E]
  const float* W_rbf = (const float*)d_in[3];  // [NR,H]
  const float* W_up  = (const float*)d_in[4];  // [H,D]
  const float* Ws    = (const float*)d_in[5];  // [L,D,D]
  const float* bs    = (const float*)d_in[6];  // [L,D]
  const float* W_out = (const float*)d_in[7];  // [D,OUT]
  float* out = (float*)d_out;                  // [B,N,OUT]

  const size_t buf_elems = (size_t)B_ * N_ * D_;  // 10,240,000 floats
  float* bufA = (float*)d_ws;
  float* bufB = bufA + buf_elems;

  // zero agg accumulator (bufA)
  hipMemsetAsync(bufA, 0, buf_elems * sizeof(float), stream);

  // scatter-add g into agg
  scatter_kernel<<<E_, 256, 0, stream>>>(x, rbf, idx, W_rbf, bufA);

  const int MB = (B_ * N_) / 64;  // 625 row blocks

  // h = agg @ W_up                      (bufA -> bufB)
  gemm_kernel<false><<<dim3(MB, D_ / 64), 256, 0, stream>>>(
      bufA, W_up, nullptr, bufB, D_);
  // h = silu(h @ Ws[0] + bs[0])         (bufB -> bufA)
  gemm_kernel<true><<<dim3(MB, D_ / 64), 256, 0, stream>>>(
      bufB, Ws + 0 * D_ * D_, bs + 0 * D_, bufA, D_);
  // h = silu(h @ Ws[1] + bs[1])         (bufA -> bufB)
  gemm_kernel<true><<<dim3(MB, D_ / 64), 256, 0, stream>>>(
      bufA, Ws + 1 * D_ * D_, bs + 1 * D_, bufB, D_);
  // h = silu(h @ Ws[2] + bs[2])         (bufB -> bufA)
  gemm_kernel<true><<<dim3(MB, D_ / 64), 256, 0, stream>>>(
      bufB, Ws + 2 * D_ * D_, bs + 2 * D_, bufA, D_);
  // out = h @ W_out                     (bufA -> d_out)
  gemm_kernel<false><<<dim3(MB, OUT_ / 64), 256, 0, stream>>>(
      bufA, W_out, nullptr, out, OUT_);
}

// Round 2
// 214.806 us; speedup vs baseline: 3.1817x; 3.1817x over previous
//
#include <hip/hip_runtime.h>
#include <hip/hip_bf16.h>

// Problem constants (fixed by reference)
#define B_  4
#define E_  100000
#define N_  10000
#define NR_ 6
#define H_  256
#define D_  256
#define OUT_ 128

typedef __attribute__((ext_vector_type(4))) float f32x4;
typedef __attribute__((ext_vector_type(8))) short bf16x8;

__device__ __forceinline__ ushort f2bf(float f) {
  unsigned u = __builtin_bit_cast(unsigned, f);
  u += 0x7fffu + ((u >> 16) & 1u);  // round-to-nearest-even
  return (ushort)(u >> 16);
}

// ---------------------------------------------------------------------------
// CSR build: histogram -> scan -> fill
// ---------------------------------------------------------------------------
__global__ __launch_bounds__(256) void hist_kernel(const int* __restrict__ idx,
                                                   int* __restrict__ counts) {
  int e = blockIdx.x * 256 + threadIdx.x;
  if (e < E_) atomicAdd(&counts[idx[e]], 1);
}

__global__ __launch_bounds__(1024) void scan_kernel(
    const int* __restrict__ counts, int* __restrict__ starts,
    int* __restrict__ cursor) {
  __shared__ int sums[1024];
  const int t = threadIdx.x;
  const int base = t * 10;
  int loc[10];
  int s = 0;
#pragma unroll
  for (int j = 0; j < 10; ++j) {
    int v = (base + j < N_) ? counts[base + j] : 0;
    loc[j] = v;
    s += v;
  }
  sums[t] = s;
  __syncthreads();
  for (int off = 1; off < 1024; off <<= 1) {
    int v = (t >= off) ? sums[t - off] : 0;
    __syncthreads();
    sums[t] += v;
    __syncthreads();
  }
  int run = sums[t] - s;  // exclusive prefix
#pragma unroll
  for (int j = 0; j < 10; ++j) {
    if (base + j < N_) {
      starts[base + j] = run;
      cursor[base + j] = run;
      run += loc[j];
    }
  }
}

__global__ __launch_bounds__(256) void fill_kernel(const int* __restrict__ idx,
                                                   int* __restrict__ cursor,
                                                   int* __restrict__ buckets) {
  int e = blockIdx.x * 256 + threadIdx.x;
  if (e < E_) {
    int pos = atomicAdd(&cursor[idx[e]], 1);
    buckets[pos] = e;
  }
}

// ---------------------------------------------------------------------------
// Gather aggregation: one block per node, 256 threads (one per h).
// agg[b][node][h] = sum_{e in bucket(node)} (rbf[e]@W_rbf)[h] * x[b][e][h]
// Output written as bf16 (input to the MFMA chain).
// ---------------------------------------------------------------------------
__global__ __launch_bounds__(256) void gather_kernel(
    const float* __restrict__ x, const float* __restrict__ rbf,
    const float* __restrict__ W_rbf, const int* __restrict__ starts,
    const int* __restrict__ counts, const int* __restrict__ buckets,
    ushort* __restrict__ agg) {
  const int node = blockIdx.x;
  const int h = threadIdx.x;

  float wr[NR_];
#pragma unroll
  for (int r = 0; r < NR_; ++r) wr[r] = W_rbf[r * H_ + h];

  float acc0 = 0.f, acc1 = 0.f, acc2 = 0.f, acc3 = 0.f;
  const int s = starts[node];
  const int d = counts[node];
  for (int j = 0; j < d; ++j) {
    const int e = buckets[s + j];
    float rp = 0.f;
#pragma unroll
    for (int r = 0; r < NR_; ++r) rp += rbf[e * NR_ + r] * wr[r];
    acc0 += x[(size_t)(0 * E_ + e) * H_ + h] * rp;
    acc1 += x[(size_t)(1 * E_ + e) * H_ + h] * rp;
    acc2 += x[(size_t)(2 * E_ + e) * H_ + h] * rp;
    acc3 += x[(size_t)(3 * E_ + e) * H_ + h] * rp;
  }
  agg[(size_t)(0 * N_ + node) * H_ + h] = f2bf(acc0);
  agg[(size_t)(1 * N_ + node) * H_ + h] = f2bf(acc1);
  agg[(size_t)(2 * N_ + node) * H_ + h] = f2bf(acc2);
  agg[(size_t)(3 * N_ + node) * H_ + h] = f2bf(acc3);
}

// ---------------------------------------------------------------------------
// Weight conversion: f32 [K][N] -> bf16 transposed [N][K], all 5 matrices.
// Concatenated dst: W_up^T(256x256) | Ws0^T | Ws1^T | Ws2^T | W_out^T(128x256)
// ---------------------------------------------------------------------------
__global__ __launch_bounds__(256) void convert_weights(
    const float* __restrict__ W_up, const float* __restrict__ Ws,
    const float* __restrict__ W_out, ushort* __restrict__ Wt) {
  const int id = blockIdx.x * 256 + threadIdx.x;  // < 294912
  const float* src;
  int base, Ncols;
  if (id < 65536) {
    src = W_up; base = 0; Ncols = 256;
  } else if (id < 4 * 65536) {
    int l = (id - 65536) >> 16;
    src = Ws + l * 65536; base = (1 + l) * 65536; Ncols = 256;
  } else {
    src = W_out; base = 4 * 65536; Ncols = 128;
  }
  const int loc = id - base;
  const int n = loc >> 8;    // dst row  (0..Ncols-1)
  const int k = loc & 255;   // dst col  (0..255)
  Wt[id] = f2bf(src[k * Ncols + n]);
}

// ---------------------------------------------------------------------------
// bf16 MFMA GEMM: C[M][Nt] = act(A[M][256] @ W[256][Nt] + bias)
// A bf16 row-major, W given transposed bf16 [Nt][256].
// BM=64 (M=40000 -> 625 blocks exact), BN=128, BK=64, 256 thr = 4 waves (2x2),
// each wave computes 32x64 via 2x4 frags of 16x16x32.
// ---------------------------------------------------------------------------
template <bool BIAS_ACT, bool OUT_F32>
__global__ __launch_bounds__(256) void gemm_mfma(
    const ushort* __restrict__ A, const ushort* __restrict__ Wt,
    const float* __restrict__ bias, void* __restrict__ Cv, int Ntotal) {
  __shared__ ushort As[64][72];    // row stride 144 B (9x16B): 2-way bank alias only
  __shared__ ushort Bs[128][72];

  const int row0 = blockIdx.x * 64;
  const int col0 = blockIdx.y * 128;
  const int tid = threadIdx.x;
  const int wave = tid >> 6;
  const int lane = tid & 63;
  const int wr = wave >> 1;        // 0..1 : 32-row strip
  const int wc = wave & 1;         // 0..1 : 64-col strip
  const int lr = lane & 15;
  const int lk = (lane >> 4) * 8;

  f32x4 acc[2][4] = {};

  for (int k0 = 0; k0 < 256; k0 += 64) {
    // stage A: 64 rows x 64 k, 512 x 16B chunks, 2 per thread
#pragma unroll
    for (int t = 0; t < 2; ++t) {
      const int id = tid + t * 256;
      const int r = id >> 3;
      const int kc = id & 7;
      const uint4 v = *reinterpret_cast<const uint4*>(
          &A[(size_t)(row0 + r) * 256 + k0 + kc * 8]);
      *reinterpret_cast<uint4*>(&As[r][kc * 8]) = v;
    }
    // stage B (transposed weights): 128 rows x 64 k, 1024 chunks, 4 per thread
#pragma unroll
    for (int t = 0; t < 4; ++t) {
      const int id = tid + t * 256;
      const int n = id >> 3;
      const int kc = id & 7;
      const uint4 v = *reinterpret_cast<const uint4*>(
          &Wt[(size_t)(col0 + n) * 256 + k0 + kc * 8]);
      *reinterpret_cast<uint4*>(&Bs[n][kc * 8]) = v;
    }
    __syncthreads();

#pragma unroll
    for (int ks = 0; ks < 64; ks += 32) {
      bf16x8 af[2], bf[4];
#pragma unroll
      for (int m = 0; m < 2; ++m)
        af[m] = *reinterpret_cast<const bf16x8*>(&As[wr * 32 + m * 16 + lr][ks + lk]);
#pragma unroll
      for (int n = 0; n < 4; ++n)
        bf[n] = *reinterpret_cast<const bf16x8*>(&Bs[wc * 64 + n * 16 + lr][ks + lk]);
#pragma unroll
      for (int m = 0; m < 2; ++m)
#pragma unroll
        for (int n = 0; n < 4; ++n)
          acc[m][n] = __builtin_amdgcn_mfma_f32_16x16x32_bf16(af[m], bf[n],
                                                              acc[m][n], 0, 0, 0);
    }
    __syncthreads();
  }

  // epilogue: C/D frag layout col=lane&15, row=(lane>>4)*4+reg
  const int rbase = row0 + wr * 32 + (lane >> 4) * 4;
  const int cbase = col0 + wc * 64 + lr;
#pragma unroll
  for (int m = 0; m < 2; ++m) {
#pragma unroll
    for (int n = 0; n < 4; ++n) {
      const int col = cbase + n * 16;
      float bv = 0.f;
      if (BIAS_ACT) bv = bias[col];
#pragma unroll
      for (int r = 0; r < 4; ++r) {
        const int row = rbase + m * 16 + r;
        float v = acc[m][n][r];
        if (BIAS_ACT) {
          v += bv;
          v = v / (1.0f + __expf(-v));  // SiLU
        }
        if (OUT_F32)
          reinterpret_cast<float*>(Cv)[(size_t)row * Ntotal + col] = v;
        else
          reinterpret_cast<ushort*>(Cv)[(size_t)row * Ntotal + col] = f2bf(v);
      }
    }
  }
}

// ---------------------------------------------------------------------------
extern "C" void kernel_launch(void* const* d_in, const int* in_sizes, int n_in,
                              void* d_out, int out_size, void* d_ws,
                              size_t ws_size, hipStream_t stream) {
  const float* x     = (const float*)d_in[0];  // [B,E,H]
  const float* rbf   = (const float*)d_in[1];  // [E,NR]
  const int*   idx   = (const int*)d_in[2];    // [E]
  const float* W_rbf = (const float*)d_in[3];  // [NR,H]
  const float* W_up  = (const float*)d_in[4];  // [H,D]
  const float* Ws    = (const float*)d_in[5];  // [L,D,D]
  const float* bs    = (const float*)d_in[6];  // [L,D]
  const float* W_out = (const float*)d_in[7];  // [D,OUT]
  float* out = (float*)d_out;                  // [B,N,OUT] f32

  // workspace layout (bytes)
  char* ws = (char*)d_ws;
  const size_t act_bytes = (size_t)B_ * N_ * D_ * sizeof(ushort);  // 20.48 MB
  ushort* aggA   = (ushort*)(ws);                          // ping
  ushort* actB   = (ushort*)(ws + act_bytes);              // pong
  ushort* Wt     = (ushort*)(ws + 2 * act_bytes);          // 294912 bf16
  char*   ibase  = ws + 2 * act_bytes + 294912 * sizeof(ushort);
  int* counts  = (int*)(ibase);
  int* starts  = (int*)(ibase + 40000);
  int* cursor  = (int*)(ibase + 80000);
  int* buckets = (int*)(ibase + 120000);

  // CSR build
  hipMemsetAsync(counts, 0, N_ * sizeof(int), stream);
  hist_kernel<<<(E_ + 255) / 256, 256, 0, stream>>>(idx, counts);
  scan_kernel<<<1, 1024, 0, stream>>>(counts, starts, cursor);
  fill_kernel<<<(E_ + 255) / 256, 256, 0, stream>>>(idx, cursor, buckets);

  // weights -> bf16 transposed (independent of CSR chain)
  convert_weights<<<294912 / 256, 256, 0, stream>>>(W_up, Ws, W_out, Wt);

  // gather-aggregate into bf16 agg
  gather_kernel<<<N_, 256, 0, stream>>>(x, rbf, W_rbf, starts, counts, buckets,
                                        aggA);

  const ushort* Wt_up  = Wt;
  const ushort* Wt_l0  = Wt + 1 * 65536;
  const ushort* Wt_l1  = Wt + 2 * 65536;
  const ushort* Wt_l2  = Wt + 3 * 65536;
  const ushort* Wt_out = Wt + 4 * 65536;

  const dim3 g256(625, 2), g128(625, 1);
  // h = agg @ W_up                         (aggA -> actB)
  gemm_mfma<false, false><<<g256, 256, 0, stream>>>(aggA, Wt_up, nullptr, actB, D_);
  // h = silu(h @ Ws[0] + bs[0])            (actB -> aggA)
  gemm_mfma<true, false><<<g256, 256, 0, stream>>>(actB, Wt_l0, bs + 0 * D_, aggA, D_);
  // h = silu(h @ Ws[1] + bs[1])            (aggA -> actB)
  gemm_mfma<true, false><<<g256, 256, 0, stream>>>(aggA, Wt_l1, bs + 1 * D_, actB, D_);
  // h = silu(h @ Ws[2] + bs[2])            (actB -> aggA)
  gemm_mfma<true, false><<<g256, 256, 0, stream>>>(actB, Wt_l2, bs + 2 * D_, aggA, D_);
  // out = h @ W_out                        (aggA -> d_out, f32)
  gemm_mfma<false, true><<<g128, 256, 0, stream>>>(aggA, Wt_out, nullptr, out, OUT_);
}